// Round 16
// baseline (224.799 us; speedup 1.0000x reference)
//
#include <hip/hip_runtime.h>

#define T_SEQ 512
#define B_BAT 256
#define ED_ 100
#define NVOC 32000
#define DT_C 1e-3f
#define SC_C 0.2f
#define MU_C 1.0f
#define NSTEP 20
#define CCH 16                // tokens per pipeline chunk
#define NCH (T_SEQ / CCH)     // 32 chunks
#define NIT (NCH + 5)         // 6 pipeline stages

typedef float v2f __attribute__((ext_vector_type(2)));
typedef float f32x4 __attribute__((ext_vector_type(4)));
typedef short bf16x8 __attribute__((ext_vector_type(8)));

#define MFMA(c_, a_, b_) \
    c_ = __builtin_amdgcn_mfma_f32_16x16x32_bf16(a_, b_, c_, 0, 0, 0)

// Packed Hopf Euler step, chain depth 3:
//   w = (-dom*zi + dcr, dom*zr + dci)   [VOP3P, op_sel half-swap]
//   h = C1*z + w
//   u = z*z ; r2 = u.x + u.y
//   ab = -DT*z
//   z' = ab*r2 + h                       [2 scalar fma]
#define HOPF_STEP(z, domv, dcv, c1v, ndtv)                                     \
    {                                                                          \
        v2f w_, u1_, ab_, h_;                                                  \
        asm("v_pk_fma_f32 %0, %1, %2, %3 op_sel:[0,1,0] op_sel_hi:[1,0,1]"     \
            : "=v"(w_) : "v"(domv), "v"(z), "v"(dcv));                         \
        asm("v_pk_mul_f32 %0, %1, %1" : "=v"(u1_) : "v"(z));                   \
        asm("v_pk_mul_f32 %0, %1, %2" : "=v"(ab_) : "v"(ndtv), "v"(z));        \
        asm("v_pk_fma_f32 %0, %1, %2, %3"                                      \
            : "=v"(h_) : "v"(c1v), "v"(z), "v"(w_));                           \
        float r2_ = u1_.x + u1_.y;                                             \
        z.x = fmaf(ab_.x, r2_, h_.x);                                          \
        z.y = fmaf(ab_.y, r2_, h_.y);                                          \
    }

__device__ __forceinline__ unsigned pack2_bf16(float a, float b) {
    unsigned r;
    asm("v_cvt_pk_bf16_f32 %0, %1, %2" : "=v"(r) : "v"(a), "v"(b));
    return r;
}

__device__ __forceinline__ float fast_tanh(float x) {
    float e = __expf(2.f * x);
    return 1.f - 2.f * __builtin_amdgcn_rcpf(e + 1.f);
}

// hopf Euler chain for one token (FULL unroll, depth-3 packed step);
// forcing from packed bf16 u32; writes bf16 hi/lo packed state to z-ring
__device__ __forceinline__ void hopf_tok(unsigned fpk, v2f& zH,
                                         v2f domv, v2f c1v, v2f ndtv,
                                         unsigned* zh, unsigned* zl, int wa) {
    const float SD = DT_C * SC_C;
    v2f dcv;
    dcv.x = SD * __uint_as_float(fpk << 16);
    dcv.y = SD * __uint_as_float(fpk & 0xFFFF0000u);
    v2f z = zH;
#pragma unroll
    for (int st = 0; st < NSTEP; ++st) HOPF_STEP(z, domv, dcv, c1v, ndtv)
    zH = z;
    unsigned hp = pack2_bf16(z.x, z.y);
    float rx = z.x - __uint_as_float(hp << 16);
    float ry = z.y - __uint_as_float(hp & 0xFFFF0000u);
    zh[wa] = hp;
    zl[wa] = pack2_bf16(rx, ry);
}

// ---------------------------------------------------------------------------
// K0: tabP[v][u] = packed bf16 (relu(E[v]@W1r+b1r)[u], relu(E[v]@W1i+b1i)[u])
// ---------------------------------------------------------------------------
__global__ __launch_bounds__(256) void k0_table(
    const float* __restrict__ E,
    const float* __restrict__ W1r, const float* __restrict__ b1r,
    const float* __restrict__ W1i, const float* __restrict__ b1i,
    unsigned* __restrict__ tabP)
{
    __shared__ float embT[128 * 104];
    __shared__ float Wc[100 * 128];
    __shared__ float bias[128];
    const int tid = threadIdx.x;
    const int row0g = blockIdx.x * 128;

    for (int idx = tid; idx < 100 * 128; idx += 256) {
        int k = idx >> 7, c = idx & 127;
        Wc[idx] = (c & 1) ? W1i[k * 64 + (c >> 1)] : W1r[k * 64 + (c >> 1)];
    }
    if (tid < 128) bias[tid] = (tid & 1) ? b1i[tid >> 1] : b1r[tid >> 1];
    {
        int r = tid >> 1, half = tid & 1;
        const float4* src = (const float4*)(E + (size_t)(row0g + r) * ED_);
        float4* dst = (float4*)&embT[r * 104];
        for (int j = half; j < 25; j += 2) dst[j] = src[j];
    }
    __syncthreads();

    const int col0 = (tid & 15) * 8;
    const int row0 = (tid >> 4) * 8;
    float acc[8][8];
#pragma unroll
    for (int i = 0; i < 8; ++i)
#pragma unroll
        for (int j = 0; j < 8; ++j) acc[i][j] = 0.f;

    for (int k0 = 0; k0 < 100; k0 += 4) {
        float ev[8][4];
#pragma unroll
        for (int i = 0; i < 8; ++i)
            *(float4*)ev[i] = *(const float4*)&embT[(row0 + i) * 104 + k0];
#pragma unroll
        for (int kk = 0; kk < 4; ++kk) {
            float4 wA = *(const float4*)&Wc[(k0 + kk) * 128 + col0];
            float4 wB = *(const float4*)&Wc[(k0 + kk) * 128 + col0 + 4];
#pragma unroll
            for (int i = 0; i < 8; ++i) {
                float e = ev[i][kk];
                acc[i][0] = fmaf(e, wA.x, acc[i][0]);
                acc[i][1] = fmaf(e, wA.y, acc[i][1]);
                acc[i][2] = fmaf(e, wA.z, acc[i][2]);
                acc[i][3] = fmaf(e, wA.w, acc[i][3]);
                acc[i][4] = fmaf(e, wB.x, acc[i][4]);
                acc[i][5] = fmaf(e, wB.y, acc[i][5]);
                acc[i][6] = fmaf(e, wB.z, acc[i][6]);
                acc[i][7] = fmaf(e, wB.w, acc[i][7]);
            }
        }
    }
#pragma unroll
    for (int i = 0; i < 8; ++i) {
        float v0 = fmaxf(acc[i][0] + bias[col0 + 0], 0.f);
        float v1 = fmaxf(acc[i][1] + bias[col0 + 1], 0.f);
        float v2 = fmaxf(acc[i][2] + bias[col0 + 2], 0.f);
        float v3 = fmaxf(acc[i][3] + bias[col0 + 3], 0.f);
        float v4 = fmaxf(acc[i][4] + bias[col0 + 4], 0.f);
        float v5 = fmaxf(acc[i][5] + bias[col0 + 5], 0.f);
        float v6 = fmaxf(acc[i][6] + bias[col0 + 6], 0.f);
        float v7 = fmaxf(acc[i][7] + bias[col0 + 7], 0.f);
        uint4 o;
        o.x = pack2_bf16(v0, v1);
        o.y = pack2_bf16(v2, v3);
        o.z = pack2_bf16(v4, v5);
        o.w = pack2_bf16(v6, v7);
        *(uint4*)&tabP[(size_t)(row0g + row0 + i) * 64 + (col0 >> 1)] = o;
    }
}

// ---------------------------------------------------------------------------
// Fused pipeline, CCH=16, transposed-MFMA GEMMs, pure-LDS hopf waves with
// depth-3 packed Euler step (round-16).
// Stages: W0 hopf1(c) | W2 h1(c-1) | W4/W6 x2(c-2) | W1 hopf2(c-3)
//         W3/W7 h2(c-4) | W5 h3+logits(c-5) + stage forcing(c+1)
// ---------------------------------------------------------------------------
__global__ __launch_bounds__(512, 1) void donn_pipe(
    const unsigned* __restrict__ tabP, const int* __restrict__ xin,
    const float* __restrict__ om1, const float* __restrict__ om2,
    const float* __restrict__ Wp1, const float* __restrict__ bp1,
    const float* __restrict__ W2r, const float* __restrict__ b2r,
    const float* __restrict__ W2i, const float* __restrict__ b2i,
    const float* __restrict__ Wp2, const float* __restrict__ bp2,
    const float* __restrict__ Wpr, const float* __restrict__ bpr,
    const float* __restrict__ Wh,  const float* __restrict__ bh,
    float* __restrict__ out)
{
    // weights (bf16 hi/lo, XOR-swizzled, transposed: [out-unit][k-pair])
    __shared__ __align__(16) unsigned WA1h[4096], WA1l[4096];   // Wp1^T 64x64
    __shared__ __align__(16) unsigned WA2h[4096], WA2l[4096];   // Wp2^T 64x64
    __shared__ __align__(16) unsigned W2Th[4096];               // W2cat^T (hi)
    __shared__ __align__(16) unsigned WPRh[1024], WPRl[1024];   // Wpr^T 32x32
    // rings (2-slot). z: [slot][token][64] u32=(zr,zi) bf16, swz lane^(tok<<2)
    __shared__ __align__(16) unsigned z1h_[2048], z1l_[2048];
    __shared__ __align__(16) unsigned z2h_[2048], z2l_[2048];
    // h1/h2: [slot][token][32] u32=(unit 2q, 2q+1), swz q^((tok&7)<<2)
    __shared__ __align__(16) unsigned h1h_[1024], h1l_[1024];
    __shared__ __align__(16) unsigned h2h_[1024], h2l_[1024];
    // x2: packed bf16 (re,im) u32 [slot][unit(64)][20 pad] rows 16B-aligned
    __shared__ __align__(16) unsigned x2p_[2 * 64 * 20];
    // layer-1 forcing ring: packed bf16 u32 [slot][unit(64)][20 pad]
    __shared__ __align__(16) unsigned fbuf[2 * 64 * 20];

    const int tid = threadIdx.x, wid = tid >> 6, lane = tid & 63;
    const int cw = lane & 15, grp = lane >> 4;
    const int b = blockIdx.x;
    const int* xb = xin + b * T_SEQ;

    // ---- stage weights into LDS ----
    for (int idx = tid; idx < 4096; idx += 512) {
        int c = idx >> 6, q = idx & 63;          // c = h-unit, q = kcat pair
        int sidx = c * 64 + (q ^ ((c & 15) << 2));
        float w0 = Wp1[q * 64 + c], w1 = Wp1[(64 + q) * 64 + c];
        unsigned h = pack2_bf16(w0, w1);
        WA1h[sidx] = h;
        WA1l[sidx] = pack2_bf16(w0 - __uint_as_float(h << 16),
                                w1 - __uint_as_float(h & 0xFFFF0000u));
        float v0 = Wp2[q * 64 + c], v1 = Wp2[(64 + q) * 64 + c];
        unsigned h2 = pack2_bf16(v0, v1);
        WA2h[sidx] = h2;
        WA2l[sidx] = pack2_bf16(v0 - __uint_as_float(h2 << 16),
                                v1 - __uint_as_float(h2 & 0xFFFF0000u));
    }
    for (int idx = tid; idx < 4096; idx += 512) {
        int c = idx >> 5, q = idx & 31;          // c = x2col, q = h1-unit pair
        const float* Wsrc = (c & 1) ? W2i : W2r;
        int u = c >> 1;
        W2Th[c * 32 + (q ^ ((c & 7) << 2))] =
            pack2_bf16(Wsrc[(2 * q) * 64 + u], Wsrc[(2 * q + 1) * 64 + u]);
    }
    for (int idx = tid; idx < 1024; idx += 512) {
        int j = idx >> 5, q = idx & 31;          // j = h3 col (pad 32)
        float w0 = (j < 20) ? Wpr[(2 * q) * 20 + j] : 0.f;
        float w1 = (j < 20) ? Wpr[(2 * q + 1) * 20 + j] : 0.f;
        unsigned h = pack2_bf16(w0, w1);
        int sidx = j * 32 + (q ^ ((j & 7) << 2));
        WPRh[sidx] = h;
        WPRl[sidx] = pack2_bf16(w0 - __uint_as_float(h << 16),
                                w1 - __uint_as_float(h & 0xFFFF0000u));
    }

    // ---- per-wave register preloads ----
    v2f zH = { 0.1f, 0.0f };
    v2f domv = { 0.f, 0.f };
    const v2f c1v  = { 1.0f + DT_C * MU_C, 1.0f + DT_C * MU_C };
    const v2f ndtv = { -DT_C, -DT_C };
    if (wid == 0) { float d = DT_C * om1[lane]; domv.x = -d; domv.y = d; }
    if (wid == 1) { float d = DT_C * om2[lane]; domv.x = -d; domv.y = d; }

    float bAv[4][4];                // W2: bp1 | W3/W7: bp2 | W4/W6: b2cat
#pragma unroll
    for (int a = 0; a < 4; ++a)
#pragma unroll
        for (int r = 0; r < 4; ++r) bAv[a][r] = 0.f;
    if (wid == 2) {
#pragma unroll
        for (int ct = 0; ct < 4; ++ct)
#pragma unroll
            for (int r = 0; r < 4; ++r) bAv[ct][r] = bp1[ct * 16 + grp * 4 + r];
    } else if (wid == 3 || wid == 7) {
        const int CT0 = (wid == 3) ? 0 : 2;
#pragma unroll
        for (int ct = 0; ct < 2; ++ct)
#pragma unroll
            for (int r = 0; r < 4; ++r)
                bAv[ct][r] = bp2[(CT0 + ct) * 16 + grp * 4 + r];
    } else if (wid == 4 || wid == 6) {
        const int RT0 = (wid == 4) ? 0 : 4;
#pragma unroll
        for (int rt = 0; rt < 4; ++rt)
#pragma unroll
            for (int r = 0; r < 4; ++r) {
                int row = (RT0 + rt) * 16 + grp * 4 + r;
                bAv[rt][r] = (row & 1) ? b2i[row >> 1] : b2r[row >> 1];
            }
    }
    float bprv0[4], bprv1[4], wh00[4], wh01[4], wh10[4], wh11[4];
    float bh0 = 0.f, bh1 = 0.f;
    if (wid == 5) {
#pragma unroll
        for (int r = 0; r < 4; ++r) {
            int j0 = grp * 4 + r;
            bprv0[r] = bpr[j0];
            wh00[r] = Wh[j0 * 2];
            wh01[r] = Wh[j0 * 2 + 1];
            int j1 = 16 + grp * 4 + r;
            bool v = (j1 < 20);
            bprv1[r] = v ? bpr[j1] : 0.f;
            wh10[r] = v ? Wh[j1 * 2] : 0.f;
            wh11[r] = v ? Wh[j1 * 2 + 1] : 0.f;
        }
        bh0 = bh[0]; bh1 = bh[1];
        // prologue: stage chunk-0 forcing into fbuf slot 0
#pragma unroll
        for (int j = 0; j < 16; ++j) {
            unsigned v = tabP[(size_t)xb[j] * 64 + lane];
            fbuf[lane * 20 + j] = v;
        }
    }
    __syncthreads();

    for (int it = 0; it < NIT; ++it) {
        if (wid == 0) {                      // hopf1, chunk it (forcing in fbuf)
            const int c = it;
            if (c < NCH) {
                const int s = c & 1;
                const unsigned* fs = fbuf + s * 1280 + lane * 20;
                uint4 q0 = *(const uint4*)(fs + 0);
                uint4 q1 = *(const uint4*)(fs + 4);
                uint4 q2 = *(const uint4*)(fs + 8);
                uint4 q3 = *(const uint4*)(fs + 12);
                unsigned fr[16] = { q0.x, q0.y, q0.z, q0.w,
                                    q1.x, q1.y, q1.z, q1.w,
                                    q2.x, q2.y, q2.z, q2.w,
                                    q3.x, q3.y, q3.z, q3.w };
                __builtin_amdgcn_s_setprio(1);
#pragma unroll
                for (int j = 0; j < 16; ++j)
                    hopf_tok(fr[j], zH, domv, c1v, ndtv, z1h_, z1l_,
                             s * 1024 + j * 64 + (lane ^ ((j & 15) << 2)));
                __builtin_amdgcn_s_setprio(0);
            }
        } else if (wid == 1) {               // hopf2, chunk it-3
            const int c = it - 3;
            if (0 <= c && c < NCH) {
                const int s = c & 1;
                const unsigned* xs = x2p_ + s * 1280 + lane * 20;
                uint4 q0 = *(const uint4*)(xs + 0);
                uint4 q1 = *(const uint4*)(xs + 4);
                uint4 q2 = *(const uint4*)(xs + 8);
                uint4 q3 = *(const uint4*)(xs + 12);
                unsigned fr[16] = { q0.x, q0.y, q0.z, q0.w,
                                    q1.x, q1.y, q1.z, q1.w,
                                    q2.x, q2.y, q2.z, q2.w,
                                    q3.x, q3.y, q3.z, q3.w };
                __builtin_amdgcn_s_setprio(1);
#pragma unroll
                for (int j = 0; j < 16; ++j)
                    hopf_tok(fr[j], zH, domv, c1v, ndtv, z2h_, z2l_,
                             s * 1024 + j * 64 + (lane ^ ((j & 15) << 2)));
                __builtin_amdgcn_s_setprio(0);
            }
        } else if (wid == 2) {               // h1^T MFMA, chunk it-1
            const int c = it - 1;
            if (0 <= c && c < NCH) {
                const int s = c & 1;
                f32x4 acc[4] = {{0,0,0,0},{0,0,0,0},{0,0,0,0},{0,0,0,0}};
#pragma unroll
                for (int ks = 0; ks < 4; ++ks) {
                    const int q0 = ks * 16 + grp * 4;
                    const int ba = s * 1024 + cw * 64 + (q0 ^ (cw << 2));
                    bf16x8 bhf = *(const bf16x8*)&z1h_[ba];
                    bf16x8 blf = *(const bf16x8*)&z1l_[ba];
#pragma unroll
                    for (int ct = 0; ct < 4; ++ct) {
                        const int aa = (ct * 16 + cw) * 64 + (q0 ^ (cw << 2));
                        bf16x8 ah = *(const bf16x8*)&WA1h[aa];
                        bf16x8 al = *(const bf16x8*)&WA1l[aa];
                        MFMA(acc[ct], ah, bhf);
                        MFMA(acc[ct], al, bhf);
                        MFMA(acc[ct], ah, blf);
                    }
                }
#pragma unroll
                for (int ct = 0; ct < 4; ++ct) {
                    float v0 = fmaxf(acc[ct][0] + bAv[ct][0], 0.f);
                    float v1 = fmaxf(acc[ct][1] + bAv[ct][1], 0.f);
                    float v2 = fmaxf(acc[ct][2] + bAv[ct][2], 0.f);
                    float v3 = fmaxf(acc[ct][3] + bAv[ct][3], 0.f);
                    unsigned h01 = pack2_bf16(v0, v1), h23 = pack2_bf16(v2, v3);
                    unsigned l01 = pack2_bf16(v0 - __uint_as_float(h01 << 16),
                                              v1 - __uint_as_float(h01 & 0xFFFF0000u));
                    unsigned l23 = pack2_bf16(v2 - __uint_as_float(h23 << 16),
                                              v3 - __uint_as_float(h23 & 0xFFFF0000u));
                    const int q = ct * 8 + grp * 2;
                    const int wa = s * 512 + cw * 32 + (q ^ ((cw & 7) << 2));
                    *(uint2*)&h1h_[wa] = (uint2){ h01, h23 };
                    *(uint2*)&h1l_[wa] = (uint2){ l01, l23 };
                }
            }
        } else if (wid == 3 || wid == 7) {   // h2^T MFMA, chunk it-4 (ct split)
            const int c = it - 4;
            if (0 <= c && c < NCH) {
                const int s = c & 1;
                const int CT0 = (wid == 3) ? 0 : 2;
                f32x4 acc[2] = {{0,0,0,0},{0,0,0,0}};
#pragma unroll
                for (int ks = 0; ks < 4; ++ks) {
                    const int q0 = ks * 16 + grp * 4;
                    const int ba = s * 1024 + cw * 64 + (q0 ^ (cw << 2));
                    bf16x8 bhf = *(const bf16x8*)&z2h_[ba];
                    bf16x8 blf = *(const bf16x8*)&z2l_[ba];
#pragma unroll
                    for (int ct = 0; ct < 2; ++ct) {
                        const int aa = ((CT0 + ct) * 16 + cw) * 64 + (q0 ^ (cw << 2));
                        bf16x8 ah = *(const bf16x8*)&WA2h[aa];
                        bf16x8 al = *(const bf16x8*)&WA2l[aa];
                        MFMA(acc[ct], ah, bhf);
                        MFMA(acc[ct], al, bhf);
                        MFMA(acc[ct], ah, blf);
                    }
                }
#pragma unroll
                for (int ct = 0; ct < 2; ++ct) {
                    float v0 = fmaxf(acc[ct][0] + bAv[ct][0], 0.f);
                    float v1 = fmaxf(acc[ct][1] + bAv[ct][1], 0.f);
                    float v2 = fmaxf(acc[ct][2] + bAv[ct][2], 0.f);
                    float v3 = fmaxf(acc[ct][3] + bAv[ct][3], 0.f);
                    unsigned h01 = pack2_bf16(v0, v1), h23 = pack2_bf16(v2, v3);
                    unsigned l01 = pack2_bf16(v0 - __uint_as_float(h01 << 16),
                                              v1 - __uint_as_float(h01 & 0xFFFF0000u));
                    unsigned l23 = pack2_bf16(v2 - __uint_as_float(h23 << 16),
                                              v3 - __uint_as_float(h23 & 0xFFFF0000u));
                    const int q = (CT0 + ct) * 8 + grp * 2;
                    const int wa = s * 512 + cw * 32 + (q ^ ((cw & 7) << 2));
                    *(uint2*)&h2h_[wa] = (uint2){ h01, h23 };
                    *(uint2*)&h2l_[wa] = (uint2){ l01, l23 };
                }
            }
        } else if (wid == 4 || wid == 6) {   // x2^T MFMA, chunk it-2 (rt split)
            const int c = it - 2;
            if (0 <= c && c < NCH) {
                const int s = c & 1;
                const int RT0 = (wid == 4) ? 0 : 4;
                f32x4 acc[4] = {{0,0,0,0},{0,0,0,0},{0,0,0,0},{0,0,0,0}};
#pragma unroll
                for (int ks = 0; ks < 2; ++ks) {
                    const int q0 = ks * 16 + grp * 4;
                    const int ba = s * 512 + cw * 32 + (q0 ^ ((cw & 7) << 2));
                    bf16x8 bhf = *(const bf16x8*)&h1h_[ba];
                    bf16x8 blf = *(const bf16x8*)&h1l_[ba];
#pragma unroll
                    for (int rt = 0; rt < 4; ++rt) {
                        const int aa = ((RT0 + rt) * 16 + cw) * 32
                                       + (q0 ^ ((cw & 7) << 2));
                        bf16x8 ah = *(const bf16x8*)&W2Th[aa];
                        MFMA(acc[rt], ah, bhf);
                        MFMA(acc[rt], ah, blf);
                    }
                }
                unsigned* xs = x2p_ + s * 1280;
#pragma unroll
                for (int rt = 0; rt < 4; ++rt) {
                    float v0 = fmaxf(acc[rt][0] + bAv[rt][0], 0.f);
                    float v1 = fmaxf(acc[rt][1] + bAv[rt][1], 0.f);
                    float v2 = fmaxf(acc[rt][2] + bAv[rt][2], 0.f);
                    float v3 = fmaxf(acc[rt][3] + bAv[rt][3], 0.f);
                    const int p0 = (RT0 + rt) * 8 + grp * 2;
                    xs[p0 * 20 + cw]       = pack2_bf16(v0, v1);
                    xs[(p0 + 1) * 20 + cw] = pack2_bf16(v2, v3);
                }
            }
        } else {                             // wid==5: h3+logits(c-5), stage(c+1)
            const int cn = it + 1;
            if (cn < NCH) {                  // stage next chunk's forcing
                const int* xc = xb + cn * 16;
                unsigned* fd = fbuf + (cn & 1) * 1280;
#pragma unroll
                for (int j = 0; j < 16; ++j) {
                    unsigned v = tabP[(size_t)xc[j] * 64 + lane];
                    fd[lane * 20 + j] = v;
                }
            }
            const int c = it - 5;
            if (0 <= c && c < NCH) {
                const int s = c & 1;
                f32x4 c0 = {0,0,0,0}, c1 = {0,0,0,0};
#pragma unroll
                for (int ks = 0; ks < 2; ++ks) {
                    const int q0 = ks * 16 + grp * 4;
                    const int swz = q0 ^ ((cw & 7) << 2);
                    const int ba = s * 512 + cw * 32 + swz;
                    bf16x8 bhf = *(const bf16x8*)&h2h_[ba];
                    bf16x8 blf = *(const bf16x8*)&h2l_[ba];
                    bf16x8 a0h = *(const bf16x8*)&WPRh[cw * 32 + swz];
                    bf16x8 a0l = *(const bf16x8*)&WPRl[cw * 32 + swz];
                    MFMA(c0, a0h, bhf); MFMA(c0, a0l, bhf); MFMA(c0, a0h, blf);
                    bf16x8 a1h = *(const bf16x8*)&WPRh[(16 + cw) * 32 + swz];
                    bf16x8 a1l = *(const bf16x8*)&WPRl[(16 + cw) * 32 + swz];
                    MFMA(c1, a1h, bhf); MFMA(c1, a1l, bhf); MFMA(c1, a1h, blf);
                }
                float p0 = 0.f, p1 = 0.f;
#pragma unroll
                for (int r = 0; r < 4; ++r) {
                    float t0 = fast_tanh(c0[r] + bprv0[r]);
                    p0 = fmaf(t0, wh00[r], p0);
                    p1 = fmaf(t0, wh01[r], p1);
                    float t1 = fast_tanh(c1[r] + bprv1[r]);
                    p0 = fmaf(t1, wh10[r], p0);
                    p1 = fmaf(t1, wh11[r], p1);
                }
                p0 += __shfl_xor(p0, 16, 64); p0 += __shfl_xor(p0, 32, 64);
                p1 += __shfl_xor(p1, 16, 64); p1 += __shfl_xor(p1, 32, 64);
                if (grp == 0) {
                    float2 o = { p0 + bh0, p1 + bh1 };
                    *(float2*)&out[(size_t)b * (T_SEQ * 2) + (c * 16 + cw) * 2] = o;
                }
            }
        }
        __syncthreads();
    }
}

// ---------------------------------------------------------------------------
extern "C" void kernel_launch(void* const* d_in, const int* in_sizes, int n_in,
                              void* d_out, int out_size, void* d_ws, size_t ws_size,
                              hipStream_t stream) {
    const int*   x   = (const int*)  d_in[0];
    const float* E   = (const float*)d_in[1];
    const float* W1r = (const float*)d_in[2];
    const float* b1r = (const float*)d_in[3];
    const float* W1i = (const float*)d_in[4];
    const float* b1i = (const float*)d_in[5];
    const float* om1 = (const float*)d_in[6];
    const float* Wp1 = (const float*)d_in[7];
    const float* bp1 = (const float*)d_in[8];
    const float* W2r = (const float*)d_in[9];
    const float* b2r = (const float*)d_in[10];
    const float* W2i = (const float*)d_in[11];
    const float* b2i = (const float*)d_in[12];
    const float* om2 = (const float*)d_in[13];
    const float* Wp2 = (const float*)d_in[14];
    const float* bp2 = (const float*)d_in[15];
    const float* Wpr = (const float*)d_in[16];
    const float* bpr = (const float*)d_in[17];
    const float* Wh  = (const float*)d_in[18];
    const float* bh  = (const float*)d_in[19];

    unsigned* tabP = (unsigned*)d_ws;   // packed bf16 table [32000][64] — 8.2 MB

    k0_table<<<NVOC / 128, 256, 0, stream>>>(E, W1r, b1r, W1i, b1i, tabP);
    donn_pipe<<<B_BAT, 512, 0, stream>>>(tabP, x, om1, om2,
                                         Wp1, bp1, W2r, b2r, W2i, b2i,
                                         Wp2, bp2, Wpr, bpr, Wh, bh,
                                         (float*)d_out);
}

// Round 17
// 220.298 us; speedup vs baseline: 1.0204x; 1.0204x over previous
//
#include <hip/hip_runtime.h>

#define T_SEQ 512
#define B_BAT 256
#define ED_ 100
#define NVOC 32000
#define DT_C 1e-3f
#define SC_C 0.2f
#define MU_C 1.0f
#define NSTEP 20
#define CCH 16                // tokens per pipeline chunk
#define NCH (T_SEQ / CCH)     // 32 chunks
#define NIT (NCH + 5)         // 6 pipeline stages

typedef float v2f __attribute__((ext_vector_type(2)));
typedef float f32x4 __attribute__((ext_vector_type(4)));
typedef short bf16x8 __attribute__((ext_vector_type(8)));

#define MFMA(c_, a_, b_) \
    c_ = __builtin_amdgcn_mfma_f32_16x16x32_bf16(a_, b_, c_, 0, 0, 0)

__device__ __forceinline__ unsigned pack2_bf16(float a, float b) {
    unsigned r;
    asm("v_cvt_pk_bf16_f32 %0, %1, %2" : "=v"(r) : "v"(a), "v"(b));
    return r;
}

__device__ __forceinline__ float fast_tanh(float x) {
    float e = __expf(2.f * x);
    return 1.f - 2.f * __builtin_amdgcn_rcpf(e + 1.f);
}

// hopf Euler chain for one token (FULL unroll, plain-C depth-3 step):
//   w  = (-dom*zi + dcr,  dom*zr + dci)    (depth 1)
//   h  = C1*z + w                          (depth 2)
//   r2 = zr^2 + zi^2                       (depth 2)
//   ab = -DT*z                             (depth 1)
//   z' = ab*r2 + h                         (depth 3)
// forcing from packed bf16 u32; writes bf16 hi/lo packed state to z-ring
__device__ __forceinline__ void hopf_tok(unsigned fpk, v2f& zH, float domH,
                                         unsigned* zh, unsigned* zl, int wa) {
    const float C1 = 1.0f + DT_C * MU_C;
    const float SD = DT_C * SC_C;
    const float dcr = SD * __uint_as_float(fpk << 16);
    const float dci = SD * __uint_as_float(fpk & 0xFFFF0000u);
    float zr = zH.x, zi = zH.y;
#pragma unroll
    for (int st = 0; st < NSTEP; ++st) {
        float wr  = fmaf(-domH, zi, dcr);
        float wi  = fmaf( domH, zr, dci);
        float hr  = fmaf(C1, zr, wr);
        float hi  = fmaf(C1, zi, wi);
        float r2  = fmaf(zr, zr, zi * zi);
        float abr = -DT_C * zr;
        float abi = -DT_C * zi;
        zr = fmaf(abr, r2, hr);
        zi = fmaf(abi, r2, hi);
    }
    zH.x = zr; zH.y = zi;
    unsigned hp = pack2_bf16(zr, zi);
    float rx = zr - __uint_as_float(hp << 16);
    float ry = zi - __uint_as_float(hp & 0xFFFF0000u);
    zh[wa] = hp;
    zl[wa] = pack2_bf16(rx, ry);
}

// ---------------------------------------------------------------------------
// K0: tabP[v][u] = packed bf16 (relu(E[v]@W1r+b1r)[u], relu(E[v]@W1i+b1i)[u])
// ---------------------------------------------------------------------------
__global__ __launch_bounds__(256) void k0_table(
    const float* __restrict__ E,
    const float* __restrict__ W1r, const float* __restrict__ b1r,
    const float* __restrict__ W1i, const float* __restrict__ b1i,
    unsigned* __restrict__ tabP)
{
    __shared__ float embT[128 * 104];
    __shared__ float Wc[100 * 128];
    __shared__ float bias[128];
    const int tid = threadIdx.x;
    const int row0g = blockIdx.x * 128;

    for (int idx = tid; idx < 100 * 128; idx += 256) {
        int k = idx >> 7, c = idx & 127;
        Wc[idx] = (c & 1) ? W1i[k * 64 + (c >> 1)] : W1r[k * 64 + (c >> 1)];
    }
    if (tid < 128) bias[tid] = (tid & 1) ? b1i[tid >> 1] : b1r[tid >> 1];
    {
        int r = tid >> 1, half = tid & 1;
        const float4* src = (const float4*)(E + (size_t)(row0g + r) * ED_);
        float4* dst = (float4*)&embT[r * 104];
        for (int j = half; j < 25; j += 2) dst[j] = src[j];
    }
    __syncthreads();

    const int col0 = (tid & 15) * 8;
    const int row0 = (tid >> 4) * 8;
    float acc[8][8];
#pragma unroll
    for (int i = 0; i < 8; ++i)
#pragma unroll
        for (int j = 0; j < 8; ++j) acc[i][j] = 0.f;

    for (int k0 = 0; k0 < 100; k0 += 4) {
        float ev[8][4];
#pragma unroll
        for (int i = 0; i < 8; ++i)
            *(float4*)ev[i] = *(const float4*)&embT[(row0 + i) * 104 + k0];
#pragma unroll
        for (int kk = 0; kk < 4; ++kk) {
            float4 wA = *(const float4*)&Wc[(k0 + kk) * 128 + col0];
            float4 wB = *(const float4*)&Wc[(k0 + kk) * 128 + col0 + 4];
#pragma unroll
            for (int i = 0; i < 8; ++i) {
                float e = ev[i][kk];
                acc[i][0] = fmaf(e, wA.x, acc[i][0]);
                acc[i][1] = fmaf(e, wA.y, acc[i][1]);
                acc[i][2] = fmaf(e, wA.z, acc[i][2]);
                acc[i][3] = fmaf(e, wA.w, acc[i][3]);
                acc[i][4] = fmaf(e, wB.x, acc[i][4]);
                acc[i][5] = fmaf(e, wB.y, acc[i][5]);
                acc[i][6] = fmaf(e, wB.z, acc[i][6]);
                acc[i][7] = fmaf(e, wB.w, acc[i][7]);
            }
        }
    }
#pragma unroll
    for (int i = 0; i < 8; ++i) {
        float v0 = fmaxf(acc[i][0] + bias[col0 + 0], 0.f);
        float v1 = fmaxf(acc[i][1] + bias[col0 + 1], 0.f);
        float v2 = fmaxf(acc[i][2] + bias[col0 + 2], 0.f);
        float v3 = fmaxf(acc[i][3] + bias[col0 + 3], 0.f);
        float v4 = fmaxf(acc[i][4] + bias[col0 + 4], 0.f);
        float v5 = fmaxf(acc[i][5] + bias[col0 + 5], 0.f);
        float v6 = fmaxf(acc[i][6] + bias[col0 + 6], 0.f);
        float v7 = fmaxf(acc[i][7] + bias[col0 + 7], 0.f);
        uint4 o;
        o.x = pack2_bf16(v0, v1);
        o.y = pack2_bf16(v2, v3);
        o.z = pack2_bf16(v4, v5);
        o.w = pack2_bf16(v6, v7);
        *(uint4*)&tabP[(size_t)(row0g + row0 + i) * 64 + (col0 >> 1)] = o;
    }
}

// ---------------------------------------------------------------------------
// Fused pipeline, CCH=16, transposed-MFMA GEMMs, pure-LDS hopf waves
// (round-17: plain-C depth-3 Euler step).
// Stages: W0 hopf1(c) | W2 h1(c-1) | W4/W6 x2(c-2) | W1 hopf2(c-3)
//         W3/W7 h2(c-4) | W5 h3+logits(c-5) + stage forcing(c+1)
// ---------------------------------------------------------------------------
__global__ __launch_bounds__(512, 1) void donn_pipe(
    const unsigned* __restrict__ tabP, const int* __restrict__ xin,
    const float* __restrict__ om1, const float* __restrict__ om2,
    const float* __restrict__ Wp1, const float* __restrict__ bp1,
    const float* __restrict__ W2r, const float* __restrict__ b2r,
    const float* __restrict__ W2i, const float* __restrict__ b2i,
    const float* __restrict__ Wp2, const float* __restrict__ bp2,
    const float* __restrict__ Wpr, const float* __restrict__ bpr,
    const float* __restrict__ Wh,  const float* __restrict__ bh,
    float* __restrict__ out)
{
    // weights (bf16 hi/lo, XOR-swizzled, transposed: [out-unit][k-pair])
    __shared__ __align__(16) unsigned WA1h[4096], WA1l[4096];   // Wp1^T 64x64
    __shared__ __align__(16) unsigned WA2h[4096], WA2l[4096];   // Wp2^T 64x64
    __shared__ __align__(16) unsigned W2Th[4096];               // W2cat^T (hi)
    __shared__ __align__(16) unsigned WPRh[1024], WPRl[1024];   // Wpr^T 32x32
    // rings (2-slot). z: [slot][token][64] u32=(zr,zi) bf16, swz lane^(tok<<2)
    __shared__ __align__(16) unsigned z1h_[2048], z1l_[2048];
    __shared__ __align__(16) unsigned z2h_[2048], z2l_[2048];
    // h1/h2: [slot][token][32] u32=(unit 2q, 2q+1), swz q^((tok&7)<<2)
    __shared__ __align__(16) unsigned h1h_[1024], h1l_[1024];
    __shared__ __align__(16) unsigned h2h_[1024], h2l_[1024];
    // x2: packed bf16 (re,im) u32 [slot][unit(64)][20 pad] rows 16B-aligned
    __shared__ __align__(16) unsigned x2p_[2 * 64 * 20];
    // layer-1 forcing ring: packed bf16 u32 [slot][unit(64)][20 pad]
    __shared__ __align__(16) unsigned fbuf[2 * 64 * 20];

    const int tid = threadIdx.x, wid = tid >> 6, lane = tid & 63;
    const int cw = lane & 15, grp = lane >> 4;
    const int b = blockIdx.x;
    const int* xb = xin + b * T_SEQ;

    // ---- stage weights into LDS ----
    for (int idx = tid; idx < 4096; idx += 512) {
        int c = idx >> 6, q = idx & 63;          // c = h-unit, q = kcat pair
        int sidx = c * 64 + (q ^ ((c & 15) << 2));
        float w0 = Wp1[q * 64 + c], w1 = Wp1[(64 + q) * 64 + c];
        unsigned h = pack2_bf16(w0, w1);
        WA1h[sidx] = h;
        WA1l[sidx] = pack2_bf16(w0 - __uint_as_float(h << 16),
                                w1 - __uint_as_float(h & 0xFFFF0000u));
        float v0 = Wp2[q * 64 + c], v1 = Wp2[(64 + q) * 64 + c];
        unsigned h2 = pack2_bf16(v0, v1);
        WA2h[sidx] = h2;
        WA2l[sidx] = pack2_bf16(v0 - __uint_as_float(h2 << 16),
                                v1 - __uint_as_float(h2 & 0xFFFF0000u));
    }
    for (int idx = tid; idx < 4096; idx += 512) {
        int c = idx >> 5, q = idx & 31;          // c = x2col, q = h1-unit pair
        const float* Wsrc = (c & 1) ? W2i : W2r;
        int u = c >> 1;
        W2Th[c * 32 + (q ^ ((c & 7) << 2))] =
            pack2_bf16(Wsrc[(2 * q) * 64 + u], Wsrc[(2 * q + 1) * 64 + u]);
    }
    for (int idx = tid; idx < 1024; idx += 512) {
        int j = idx >> 5, q = idx & 31;          // j = h3 col (pad 32)
        float w0 = (j < 20) ? Wpr[(2 * q) * 20 + j] : 0.f;
        float w1 = (j < 20) ? Wpr[(2 * q + 1) * 20 + j] : 0.f;
        unsigned h = pack2_bf16(w0, w1);
        int sidx = j * 32 + (q ^ ((j & 7) << 2));
        WPRh[sidx] = h;
        WPRl[sidx] = pack2_bf16(w0 - __uint_as_float(h << 16),
                                w1 - __uint_as_float(h & 0xFFFF0000u));
    }

    // ---- per-wave register preloads ----
    float domH = 0.f;
    v2f zH = { 0.1f, 0.0f };
    if (wid == 0) domH = DT_C * om1[lane];
    if (wid == 1) domH = DT_C * om2[lane];

    float bAv[4][4];                // W2: bp1 | W3/W7: bp2 | W4/W6: b2cat
#pragma unroll
    for (int a = 0; a < 4; ++a)
#pragma unroll
        for (int r = 0; r < 4; ++r) bAv[a][r] = 0.f;
    if (wid == 2) {
#pragma unroll
        for (int ct = 0; ct < 4; ++ct)
#pragma unroll
            for (int r = 0; r < 4; ++r) bAv[ct][r] = bp1[ct * 16 + grp * 4 + r];
    } else if (wid == 3 || wid == 7) {
        const int CT0 = (wid == 3) ? 0 : 2;
#pragma unroll
        for (int ct = 0; ct < 2; ++ct)
#pragma unroll
            for (int r = 0; r < 4; ++r)
                bAv[ct][r] = bp2[(CT0 + ct) * 16 + grp * 4 + r];
    } else if (wid == 4 || wid == 6) {
        const int RT0 = (wid == 4) ? 0 : 4;
#pragma unroll
        for (int rt = 0; rt < 4; ++rt)
#pragma unroll
            for (int r = 0; r < 4; ++r) {
                int row = (RT0 + rt) * 16 + grp * 4 + r;
                bAv[rt][r] = (row & 1) ? b2i[row >> 1] : b2r[row >> 1];
            }
    }
    float bprv0[4], bprv1[4], wh00[4], wh01[4], wh10[4], wh11[4];
    float bh0 = 0.f, bh1 = 0.f;
    if (wid == 5) {
#pragma unroll
        for (int r = 0; r < 4; ++r) {
            int j0 = grp * 4 + r;
            bprv0[r] = bpr[j0];
            wh00[r] = Wh[j0 * 2];
            wh01[r] = Wh[j0 * 2 + 1];
            int j1 = 16 + grp * 4 + r;
            bool v = (j1 < 20);
            bprv1[r] = v ? bpr[j1] : 0.f;
            wh10[r] = v ? Wh[j1 * 2] : 0.f;
            wh11[r] = v ? Wh[j1 * 2 + 1] : 0.f;
        }
        bh0 = bh[0]; bh1 = bh[1];
        // prologue: stage chunk-0 forcing into fbuf slot 0
#pragma unroll
        for (int j = 0; j < 16; ++j) {
            unsigned v = tabP[(size_t)xb[j] * 64 + lane];
            fbuf[lane * 20 + j] = v;
        }
    }
    __syncthreads();

    for (int it = 0; it < NIT; ++it) {
        if (wid == 0) {                      // hopf1, chunk it (forcing in fbuf)
            const int c = it;
            if (c < NCH) {
                const int s = c & 1;
                const unsigned* fs = fbuf + s * 1280 + lane * 20;
                uint4 q0 = *(const uint4*)(fs + 0);
                uint4 q1 = *(const uint4*)(fs + 4);
                uint4 q2 = *(const uint4*)(fs + 8);
                uint4 q3 = *(const uint4*)(fs + 12);
                unsigned fr[16] = { q0.x, q0.y, q0.z, q0.w,
                                    q1.x, q1.y, q1.z, q1.w,
                                    q2.x, q2.y, q2.z, q2.w,
                                    q3.x, q3.y, q3.z, q3.w };
                __builtin_amdgcn_s_setprio(1);
#pragma unroll
                for (int j = 0; j < 16; ++j)
                    hopf_tok(fr[j], zH, domH, z1h_, z1l_,
                             s * 1024 + j * 64 + (lane ^ ((j & 15) << 2)));
                __builtin_amdgcn_s_setprio(0);
            }
        } else if (wid == 1) {               // hopf2, chunk it-3
            const int c = it - 3;
            if (0 <= c && c < NCH) {
                const int s = c & 1;
                const unsigned* xs = x2p_ + s * 1280 + lane * 20;
                uint4 q0 = *(const uint4*)(xs + 0);
                uint4 q1 = *(const uint4*)(xs + 4);
                uint4 q2 = *(const uint4*)(xs + 8);
                uint4 q3 = *(const uint4*)(xs + 12);
                unsigned fr[16] = { q0.x, q0.y, q0.z, q0.w,
                                    q1.x, q1.y, q1.z, q1.w,
                                    q2.x, q2.y, q2.z, q2.w,
                                    q3.x, q3.y, q3.z, q3.w };
                __builtin_amdgcn_s_setprio(1);
#pragma unroll
                for (int j = 0; j < 16; ++j)
                    hopf_tok(fr[j], zH, domH, z2h_, z2l_,
                             s * 1024 + j * 64 + (lane ^ ((j & 15) << 2)));
                __builtin_amdgcn_s_setprio(0);
            }
        } else if (wid == 2) {               // h1^T MFMA, chunk it-1
            const int c = it - 1;
            if (0 <= c && c < NCH) {
                const int s = c & 1;
                f32x4 acc[4] = {{0,0,0,0},{0,0,0,0},{0,0,0,0},{0,0,0,0}};
#pragma unroll
                for (int ks = 0; ks < 4; ++ks) {
                    const int q0 = ks * 16 + grp * 4;
                    const int ba = s * 1024 + cw * 64 + (q0 ^ (cw << 2));
                    bf16x8 bhf = *(const bf16x8*)&z1h_[ba];
                    bf16x8 blf = *(const bf16x8*)&z1l_[ba];
#pragma unroll
                    for (int ct = 0; ct < 4; ++ct) {
                        const int aa = (ct * 16 + cw) * 64 + (q0 ^ (cw << 2));
                        bf16x8 ah = *(const bf16x8*)&WA1h[aa];
                        bf16x8 al = *(const bf16x8*)&WA1l[aa];
                        MFMA(acc[ct], ah, bhf);
                        MFMA(acc[ct], al, bhf);
                        MFMA(acc[ct], ah, blf);
                    }
                }
#pragma unroll
                for (int ct = 0; ct < 4; ++ct) {
                    float v0 = fmaxf(acc[ct][0] + bAv[ct][0], 0.f);
                    float v1 = fmaxf(acc[ct][1] + bAv[ct][1], 0.f);
                    float v2 = fmaxf(acc[ct][2] + bAv[ct][2], 0.f);
                    float v3 = fmaxf(acc[ct][3] + bAv[ct][3], 0.f);
                    unsigned h01 = pack2_bf16(v0, v1), h23 = pack2_bf16(v2, v3);
                    unsigned l01 = pack2_bf16(v0 - __uint_as_float(h01 << 16),
                                              v1 - __uint_as_float(h01 & 0xFFFF0000u));
                    unsigned l23 = pack2_bf16(v2 - __uint_as_float(h23 << 16),
                                              v3 - __uint_as_float(h23 & 0xFFFF0000u));
                    const int q = ct * 8 + grp * 2;
                    const int wa = s * 512 + cw * 32 + (q ^ ((cw & 7) << 2));
                    *(uint2*)&h1h_[wa] = (uint2){ h01, h23 };
                    *(uint2*)&h1l_[wa] = (uint2){ l01, l23 };
                }
            }
        } else if (wid == 3 || wid == 7) {   // h2^T MFMA, chunk it-4 (ct split)
            const int c = it - 4;
            if (0 <= c && c < NCH) {
                const int s = c & 1;
                const int CT0 = (wid == 3) ? 0 : 2;
                f32x4 acc[2] = {{0,0,0,0},{0,0,0,0}};
#pragma unroll
                for (int ks = 0; ks < 4; ++ks) {
                    const int q0 = ks * 16 + grp * 4;
                    const int ba = s * 1024 + cw * 64 + (q0 ^ (cw << 2));
                    bf16x8 bhf = *(const bf16x8*)&z2h_[ba];
                    bf16x8 blf = *(const bf16x8*)&z2l_[ba];
#pragma unroll
                    for (int ct = 0; ct < 2; ++ct) {
                        const int aa = ((CT0 + ct) * 16 + cw) * 64 + (q0 ^ (cw << 2));
                        bf16x8 ah = *(const bf16x8*)&WA2h[aa];
                        bf16x8 al = *(const bf16x8*)&WA2l[aa];
                        MFMA(acc[ct], ah, bhf);
                        MFMA(acc[ct], al, bhf);
                        MFMA(acc[ct], ah, blf);
                    }
                }
#pragma unroll
                for (int ct = 0; ct < 2; ++ct) {
                    float v0 = fmaxf(acc[ct][0] + bAv[ct][0], 0.f);
                    float v1 = fmaxf(acc[ct][1] + bAv[ct][1], 0.f);
                    float v2 = fmaxf(acc[ct][2] + bAv[ct][2], 0.f);
                    float v3 = fmaxf(acc[ct][3] + bAv[ct][3], 0.f);
                    unsigned h01 = pack2_bf16(v0, v1), h23 = pack2_bf16(v2, v3);
                    unsigned l01 = pack2_bf16(v0 - __uint_as_float(h01 << 16),
                                              v1 - __uint_as_float(h01 & 0xFFFF0000u));
                    unsigned l23 = pack2_bf16(v2 - __uint_as_float(h23 << 16),
                                              v3 - __uint_as_float(h23 & 0xFFFF0000u));
                    const int q = (CT0 + ct) * 8 + grp * 2;
                    const int wa = s * 512 + cw * 32 + (q ^ ((cw & 7) << 2));
                    *(uint2*)&h2h_[wa] = (uint2){ h01, h23 };
                    *(uint2*)&h2l_[wa] = (uint2){ l01, l23 };
                }
            }
        } else if (wid == 4 || wid == 6) {   // x2^T MFMA, chunk it-2 (rt split)
            const int c = it - 2;
            if (0 <= c && c < NCH) {
                const int s = c & 1;
                const int RT0 = (wid == 4) ? 0 : 4;
                f32x4 acc[4] = {{0,0,0,0},{0,0,0,0},{0,0,0,0},{0,0,0,0}};
#pragma unroll
                for (int ks = 0; ks < 2; ++ks) {
                    const int q0 = ks * 16 + grp * 4;
                    const int ba = s * 512 + cw * 32 + (q0 ^ ((cw & 7) << 2));
                    bf16x8 bhf = *(const bf16x8*)&h1h_[ba];
                    bf16x8 blf = *(const bf16x8*)&h1l_[ba];
#pragma unroll
                    for (int rt = 0; rt < 4; ++rt) {
                        const int aa = ((RT0 + rt) * 16 + cw) * 32
                                       + (q0 ^ ((cw & 7) << 2));
                        bf16x8 ah = *(const bf16x8*)&W2Th[aa];
                        MFMA(acc[rt], ah, bhf);
                        MFMA(acc[rt], ah, blf);
                    }
                }
                unsigned* xs = x2p_ + s * 1280;
#pragma unroll
                for (int rt = 0; rt < 4; ++rt) {
                    float v0 = fmaxf(acc[rt][0] + bAv[rt][0], 0.f);
                    float v1 = fmaxf(acc[rt][1] + bAv[rt][1], 0.f);
                    float v2 = fmaxf(acc[rt][2] + bAv[rt][2], 0.f);
                    float v3 = fmaxf(acc[rt][3] + bAv[rt][3], 0.f);
                    const int p0 = (RT0 + rt) * 8 + grp * 2;
                    xs[p0 * 20 + cw]       = pack2_bf16(v0, v1);
                    xs[(p0 + 1) * 20 + cw] = pack2_bf16(v2, v3);
                }
            }
        } else {                             // wid==5: h3+logits(c-5), stage(c+1)
            const int cn = it + 1;
            if (cn < NCH) {                  // stage next chunk's forcing
                const int* xc = xb + cn * 16;
                unsigned* fd = fbuf + (cn & 1) * 1280;
#pragma unroll
                for (int j = 0; j < 16; ++j) {
                    unsigned v = tabP[(size_t)xc[j] * 64 + lane];
                    fd[lane * 20 + j] = v;
                }
            }
            const int c = it - 5;
            if (0 <= c && c < NCH) {
                const int s = c & 1;
                f32x4 c0 = {0,0,0,0}, c1 = {0,0,0,0};
#pragma unroll
                for (int ks = 0; ks < 2; ++ks) {
                    const int q0 = ks * 16 + grp * 4;
                    const int swz = q0 ^ ((cw & 7) << 2);
                    const int ba = s * 512 + cw * 32 + swz;
                    bf16x8 bhf = *(const bf16x8*)&h2h_[ba];
                    bf16x8 blf = *(const bf16x8*)&h2l_[ba];
                    bf16x8 a0h = *(const bf16x8*)&WPRh[cw * 32 + swz];
                    bf16x8 a0l = *(const bf16x8*)&WPRl[cw * 32 + swz];
                    MFMA(c0, a0h, bhf); MFMA(c0, a0l, bhf); MFMA(c0, a0h, blf);
                    bf16x8 a1h = *(const bf16x8*)&WPRh[(16 + cw) * 32 + swz];
                    bf16x8 a1l = *(const bf16x8*)&WPRl[(16 + cw) * 32 + swz];
                    MFMA(c1, a1h, bhf); MFMA(c1, a1l, bhf); MFMA(c1, a1h, blf);
                }
                float p0 = 0.f, p1 = 0.f;
#pragma unroll
                for (int r = 0; r < 4; ++r) {
                    float t0 = fast_tanh(c0[r] + bprv0[r]);
                    p0 = fmaf(t0, wh00[r], p0);
                    p1 = fmaf(t0, wh01[r], p1);
                    float t1 = fast_tanh(c1[r] + bprv1[r]);
                    p0 = fmaf(t1, wh10[r], p0);
                    p1 = fmaf(t1, wh11[r], p1);
                }
                p0 += __shfl_xor(p0, 16, 64); p0 += __shfl_xor(p0, 32, 64);
                p1 += __shfl_xor(p1, 16, 64); p1 += __shfl_xor(p1, 32, 64);
                if (grp == 0) {
                    float2 o = { p0 + bh0, p1 + bh1 };
                    *(float2*)&out[(size_t)b * (T_SEQ * 2) + (c * 16 + cw) * 2] = o;
                }
            }
        }
        __syncthreads();
    }
}

// ---------------------------------------------------------------------------
extern "C" void kernel_launch(void* const* d_in, const int* in_sizes, int n_in,
                              void* d_out, int out_size, void* d_ws, size_t ws_size,
                              hipStream_t stream) {
    const int*   x   = (const int*)  d_in[0];
    const float* E   = (const float*)d_in[1];
    const float* W1r = (const float*)d_in[2];
    const float* b1r = (const float*)d_in[3];
    const float* W1i = (const float*)d_in[4];
    const float* b1i = (const float*)d_in[5];
    const float* om1 = (const float*)d_in[6];
    const float* Wp1 = (const float*)d_in[7];
    const float* bp1 = (const float*)d_in[8];
    const float* W2r = (const float*)d_in[9];
    const float* b2r = (const float*)d_in[10];
    const float* W2i = (const float*)d_in[11];
    const float* b2i = (const float*)d_in[12];
    const float* om2 = (const float*)d_in[13];
    const float* Wp2 = (const float*)d_in[14];
    const float* bp2 = (const float*)d_in[15];
    const float* Wpr = (const float*)d_in[16];
    const float* bpr = (const float*)d_in[17];
    const float* Wh  = (const float*)d_in[18];
    const float* bh  = (const float*)d_in[19];

    unsigned* tabP = (unsigned*)d_ws;   // packed bf16 table [32000][64] — 8.2 MB

    k0_table<<<NVOC / 128, 256, 0, stream>>>(E, W1r, b1r, W1i, b1i, tabP);
    donn_pipe<<<B_BAT, 512, 0, stream>>>(tabP, x, om1, om2,
                                         Wp1, bp1, W2r, b2r, W2i, b2i,
                                         Wp2, bp2, Wpr, bpr, Wh, bh,
                                         (float*)d_out);
}

// Round 18
// 167.912 us; speedup vs baseline: 1.3388x; 1.3120x over previous
//
#include <hip/hip_runtime.h>

#define T_SEQ 512
#define B_BAT 256
#define ED_ 100
#define NVOC 32000
#define DT_C 1e-3f
#define SC_C 0.2f
#define MU_C 1.0f
#define NSTEP 20
#define CCH 16                // tokens per pipeline chunk
#define NCH (T_SEQ / CCH)     // 32 chunks
#define NIT (NCH + 5)         // 6 pipeline stages

typedef float v2f __attribute__((ext_vector_type(2)));
typedef float f32x4 __attribute__((ext_vector_type(4)));
typedef short bf16x8 __attribute__((ext_vector_type(8)));

#define MFMA(c_, a_, b_) \
    c_ = __builtin_amdgcn_mfma_f32_16x16x32_bf16(a_, b_, c_, 0, 0, 0)

__device__ __forceinline__ unsigned pack2_bf16(float a, float b) {
    unsigned r;
    asm("v_cvt_pk_bf16_f32 %0, %1, %2" : "=v"(r) : "v"(a), "v"(b));
    return r;
}

__device__ __forceinline__ float fast_tanh(float x) {
    float e = __expf(2.f * x);
    return 1.f - 2.f * __builtin_amdgcn_rcpf(e + 1.f);
}

// hopf Euler chain for one token (FULL unroll, depth-4 g-form step — the
// round-15 verified optimum; depth-3 variants regressed twice);
// forcing from packed bf16 u32; writes bf16 hi/lo packed state to z-ring
__device__ __forceinline__ void hopf_tok(unsigned fpk, v2f& zH, float domH,
                                         unsigned* zh, unsigned* zl, int wa) {
    const float C1 = 1.0f + DT_C * MU_C;
    const float SD = DT_C * SC_C;
    const float dcr = SD * __uint_as_float(fpk << 16);
    const float dci = SD * __uint_as_float(fpk & 0xFFFF0000u);
    float zr = zH.x, zi = zH.y;
#pragma unroll
    for (int st = 0; st < NSTEP; ++st) {
        float wr = fmaf(-domH, zi, dcr);
        float wi = fmaf( domH, zr, dci);
        float r2 = fmaf(zr, zr, zi * zi);
        float g  = fmaf(-DT_C, r2, C1);
        zr = fmaf(g, zr, wr);
        zi = fmaf(g, zi, wi);
    }
    zH.x = zr; zH.y = zi;
    unsigned hp = pack2_bf16(zr, zi);
    float rx = zr - __uint_as_float(hp << 16);
    float ry = zi - __uint_as_float(hp & 0xFFFF0000u);
    zh[wa] = hp;
    zl[wa] = pack2_bf16(rx, ry);
}

// ---------------------------------------------------------------------------
// K0: tabP[v][u] = packed bf16 (relu(E[v]@W1r+b1r)[u], relu(E[v]@W1i+b1i)[u])
// ---------------------------------------------------------------------------
__global__ __launch_bounds__(256) void k0_table(
    const float* __restrict__ E,
    const float* __restrict__ W1r, const float* __restrict__ b1r,
    const float* __restrict__ W1i, const float* __restrict__ b1i,
    unsigned* __restrict__ tabP)
{
    __shared__ float embT[128 * 104];
    __shared__ float Wc[100 * 128];
    __shared__ float bias[128];
    const int tid = threadIdx.x;
    const int row0g = blockIdx.x * 128;

    for (int idx = tid; idx < 100 * 128; idx += 256) {
        int k = idx >> 7, c = idx & 127;
        Wc[idx] = (c & 1) ? W1i[k * 64 + (c >> 1)] : W1r[k * 64 + (c >> 1)];
    }
    if (tid < 128) bias[tid] = (tid & 1) ? b1i[tid >> 1] : b1r[tid >> 1];
    {
        int r = tid >> 1, half = tid & 1;
        const float4* src = (const float4*)(E + (size_t)(row0g + r) * ED_);
        float4* dst = (float4*)&embT[r * 104];
        for (int j = half; j < 25; j += 2) dst[j] = src[j];
    }
    __syncthreads();

    const int col0 = (tid & 15) * 8;
    const int row0 = (tid >> 4) * 8;
    float acc[8][8];
#pragma unroll
    for (int i = 0; i < 8; ++i)
#pragma unroll
        for (int j = 0; j < 8; ++j) acc[i][j] = 0.f;

    for (int k0 = 0; k0 < 100; k0 += 4) {
        float ev[8][4];
#pragma unroll
        for (int i = 0; i < 8; ++i)
            *(float4*)ev[i] = *(const float4*)&embT[(row0 + i) * 104 + k0];
#pragma unroll
        for (int kk = 0; kk < 4; ++kk) {
            float4 wA = *(const float4*)&Wc[(k0 + kk) * 128 + col0];
            float4 wB = *(const float4*)&Wc[(k0 + kk) * 128 + col0 + 4];
#pragma unroll
            for (int i = 0; i < 8; ++i) {
                float e = ev[i][kk];
                acc[i][0] = fmaf(e, wA.x, acc[i][0]);
                acc[i][1] = fmaf(e, wA.y, acc[i][1]);
                acc[i][2] = fmaf(e, wA.z, acc[i][2]);
                acc[i][3] = fmaf(e, wA.w, acc[i][3]);
                acc[i][4] = fmaf(e, wB.x, acc[i][4]);
                acc[i][5] = fmaf(e, wB.y, acc[i][5]);
                acc[i][6] = fmaf(e, wB.z, acc[i][6]);
                acc[i][7] = fmaf(e, wB.w, acc[i][7]);
            }
        }
    }
#pragma unroll
    for (int i = 0; i < 8; ++i) {
        float v0 = fmaxf(acc[i][0] + bias[col0 + 0], 0.f);
        float v1 = fmaxf(acc[i][1] + bias[col0 + 1], 0.f);
        float v2 = fmaxf(acc[i][2] + bias[col0 + 2], 0.f);
        float v3 = fmaxf(acc[i][3] + bias[col0 + 3], 0.f);
        float v4 = fmaxf(acc[i][4] + bias[col0 + 4], 0.f);
        float v5 = fmaxf(acc[i][5] + bias[col0 + 5], 0.f);
        float v6 = fmaxf(acc[i][6] + bias[col0 + 6], 0.f);
        float v7 = fmaxf(acc[i][7] + bias[col0 + 7], 0.f);
        uint4 o;
        o.x = pack2_bf16(v0, v1);
        o.y = pack2_bf16(v2, v3);
        o.z = pack2_bf16(v4, v5);
        o.w = pack2_bf16(v6, v7);
        *(uint4*)&tabP[(size_t)(row0g + row0 + i) * 64 + (col0 >> 1)] = o;
    }
}

// ---------------------------------------------------------------------------
// Fused pipeline, CCH=16, transposed-MFMA GEMMs, pure-LDS hopf waves.
// (Round-15 configuration — verified best: 168 us.)
// Stages: W0 hopf1(c) | W2 h1(c-1) | W4/W6 x2(c-2) | W1 hopf2(c-3)
//         W3/W7 h2(c-4) | W5 h3+logits(c-5) + stage forcing(c+1)
// ---------------------------------------------------------------------------
__global__ __launch_bounds__(512, 1) void donn_pipe(
    const unsigned* __restrict__ tabP, const int* __restrict__ xin,
    const float* __restrict__ om1, const float* __restrict__ om2,
    const float* __restrict__ Wp1, const float* __restrict__ bp1,
    const float* __restrict__ W2r, const float* __restrict__ b2r,
    const float* __restrict__ W2i, const float* __restrict__ b2i,
    const float* __restrict__ Wp2, const float* __restrict__ bp2,
    const float* __restrict__ Wpr, const float* __restrict__ bpr,
    const float* __restrict__ Wh,  const float* __restrict__ bh,
    float* __restrict__ out)
{
    // weights (bf16 hi/lo, XOR-swizzled, transposed: [out-unit][k-pair])
    __shared__ __align__(16) unsigned WA1h[4096], WA1l[4096];   // Wp1^T 64x64
    __shared__ __align__(16) unsigned WA2h[4096], WA2l[4096];   // Wp2^T 64x64
    __shared__ __align__(16) unsigned W2Th[4096];               // W2cat^T (hi)
    __shared__ __align__(16) unsigned WPRh[1024], WPRl[1024];   // Wpr^T 32x32
    // rings (2-slot). z: [slot][token][64] u32=(zr,zi) bf16, swz lane^(tok<<2)
    __shared__ __align__(16) unsigned z1h_[2048], z1l_[2048];
    __shared__ __align__(16) unsigned z2h_[2048], z2l_[2048];
    // h1/h2: [slot][token][32] u32=(unit 2q, 2q+1), swz q^((tok&7)<<2)
    __shared__ __align__(16) unsigned h1h_[1024], h1l_[1024];
    __shared__ __align__(16) unsigned h2h_[1024], h2l_[1024];
    // x2: packed bf16 (re,im) u32 [slot][unit(64)][20 pad] rows 16B-aligned
    __shared__ __align__(16) unsigned x2p_[2 * 64 * 20];
    // layer-1 forcing ring: packed bf16 u32 [slot][unit(64)][20 pad]
    __shared__ __align__(16) unsigned fbuf[2 * 64 * 20];

    const int tid = threadIdx.x, wid = tid >> 6, lane = tid & 63;
    const int cw = lane & 15, grp = lane >> 4;
    const int b = blockIdx.x;
    const int* xb = xin + b * T_SEQ;

    // ---- stage weights into LDS ----
    for (int idx = tid; idx < 4096; idx += 512) {
        int c = idx >> 6, q = idx & 63;          // c = h-unit, q = kcat pair
        int sidx = c * 64 + (q ^ ((c & 15) << 2));
        float w0 = Wp1[q * 64 + c], w1 = Wp1[(64 + q) * 64 + c];
        unsigned h = pack2_bf16(w0, w1);
        WA1h[sidx] = h;
        WA1l[sidx] = pack2_bf16(w0 - __uint_as_float(h << 16),
                                w1 - __uint_as_float(h & 0xFFFF0000u));
        float v0 = Wp2[q * 64 + c], v1 = Wp2[(64 + q) * 64 + c];
        unsigned h2 = pack2_bf16(v0, v1);
        WA2h[sidx] = h2;
        WA2l[sidx] = pack2_bf16(v0 - __uint_as_float(h2 << 16),
                                v1 - __uint_as_float(h2 & 0xFFFF0000u));
    }
    for (int idx = tid; idx < 4096; idx += 512) {
        int c = idx >> 5, q = idx & 31;          // c = x2col, q = h1-unit pair
        const float* Wsrc = (c & 1) ? W2i : W2r;
        int u = c >> 1;
        W2Th[c * 32 + (q ^ ((c & 7) << 2))] =
            pack2_bf16(Wsrc[(2 * q) * 64 + u], Wsrc[(2 * q + 1) * 64 + u]);
    }
    for (int idx = tid; idx < 1024; idx += 512) {
        int j = idx >> 5, q = idx & 31;          // j = h3 col (pad 32)
        float w0 = (j < 20) ? Wpr[(2 * q) * 20 + j] : 0.f;
        float w1 = (j < 20) ? Wpr[(2 * q + 1) * 20 + j] : 0.f;
        unsigned h = pack2_bf16(w0, w1);
        int sidx = j * 32 + (q ^ ((j & 7) << 2));
        WPRh[sidx] = h;
        WPRl[sidx] = pack2_bf16(w0 - __uint_as_float(h << 16),
                                w1 - __uint_as_float(h & 0xFFFF0000u));
    }

    // ---- per-wave register preloads ----
    float domH = 0.f;
    v2f zH = { 0.1f, 0.0f };
    if (wid == 0) domH = DT_C * om1[lane];
    if (wid == 1) domH = DT_C * om2[lane];

    float bAv[4][4];                // W2: bp1 | W3/W7: bp2 | W4/W6: b2cat
#pragma unroll
    for (int a = 0; a < 4; ++a)
#pragma unroll
        for (int r = 0; r < 4; ++r) bAv[a][r] = 0.f;
    if (wid == 2) {
#pragma unroll
        for (int ct = 0; ct < 4; ++ct)
#pragma unroll
            for (int r = 0; r < 4; ++r) bAv[ct][r] = bp1[ct * 16 + grp * 4 + r];
    } else if (wid == 3 || wid == 7) {
        const int CT0 = (wid == 3) ? 0 : 2;
#pragma unroll
        for (int ct = 0; ct < 2; ++ct)
#pragma unroll
            for (int r = 0; r < 4; ++r)
                bAv[ct][r] = bp2[(CT0 + ct) * 16 + grp * 4 + r];
    } else if (wid == 4 || wid == 6) {
        const int RT0 = (wid == 4) ? 0 : 4;
#pragma unroll
        for (int rt = 0; rt < 4; ++rt)
#pragma unroll
            for (int r = 0; r < 4; ++r) {
                int row = (RT0 + rt) * 16 + grp * 4 + r;
                bAv[rt][r] = (row & 1) ? b2i[row >> 1] : b2r[row >> 1];
            }
    }
    float bprv0[4], bprv1[4], wh00[4], wh01[4], wh10[4], wh11[4];
    float bh0 = 0.f, bh1 = 0.f;
    if (wid == 5) {
#pragma unroll
        for (int r = 0; r < 4; ++r) {
            int j0 = grp * 4 + r;
            bprv0[r] = bpr[j0];
            wh00[r] = Wh[j0 * 2];
            wh01[r] = Wh[j0 * 2 + 1];
            int j1 = 16 + grp * 4 + r;
            bool v = (j1 < 20);
            bprv1[r] = v ? bpr[j1] : 0.f;
            wh10[r] = v ? Wh[j1 * 2] : 0.f;
            wh11[r] = v ? Wh[j1 * 2 + 1] : 0.f;
        }
        bh0 = bh[0]; bh1 = bh[1];
        // prologue: stage chunk-0 forcing into fbuf slot 0
#pragma unroll
        for (int j = 0; j < 16; ++j) {
            unsigned v = tabP[(size_t)xb[j] * 64 + lane];
            fbuf[lane * 20 + j] = v;
        }
    }
    __syncthreads();

    for (int it = 0; it < NIT; ++it) {
        if (wid == 0) {                      // hopf1, chunk it (forcing in fbuf)
            const int c = it;
            if (c < NCH) {
                const int s = c & 1;
                const unsigned* fs = fbuf + s * 1280 + lane * 20;
                uint4 q0 = *(const uint4*)(fs + 0);
                uint4 q1 = *(const uint4*)(fs + 4);
                uint4 q2 = *(const uint4*)(fs + 8);
                uint4 q3 = *(const uint4*)(fs + 12);
                unsigned fr[16] = { q0.x, q0.y, q0.z, q0.w,
                                    q1.x, q1.y, q1.z, q1.w,
                                    q2.x, q2.y, q2.z, q2.w,
                                    q3.x, q3.y, q3.z, q3.w };
                __builtin_amdgcn_s_setprio(1);
#pragma unroll
                for (int j = 0; j < 16; ++j)
                    hopf_tok(fr[j], zH, domH, z1h_, z1l_,
                             s * 1024 + j * 64 + (lane ^ ((j & 15) << 2)));
                __builtin_amdgcn_s_setprio(0);
            }
        } else if (wid == 1) {               // hopf2, chunk it-3
            const int c = it - 3;
            if (0 <= c && c < NCH) {
                const int s = c & 1;
                const unsigned* xs = x2p_ + s * 1280 + lane * 20;
                uint4 q0 = *(const uint4*)(xs + 0);
                uint4 q1 = *(const uint4*)(xs + 4);
                uint4 q2 = *(const uint4*)(xs + 8);
                uint4 q3 = *(const uint4*)(xs + 12);
                unsigned fr[16] = { q0.x, q0.y, q0.z, q0.w,
                                    q1.x, q1.y, q1.z, q1.w,
                                    q2.x, q2.y, q2.z, q2.w,
                                    q3.x, q3.y, q3.z, q3.w };
                __builtin_amdgcn_s_setprio(1);
#pragma unroll
                for (int j = 0; j < 16; ++j)
                    hopf_tok(fr[j], zH, domH, z2h_, z2l_,
                             s * 1024 + j * 64 + (lane ^ ((j & 15) << 2)));
                __builtin_amdgcn_s_setprio(0);
            }
        } else if (wid == 2) {               // h1^T MFMA, chunk it-1
            const int c = it - 1;
            if (0 <= c && c < NCH) {
                const int s = c & 1;
                f32x4 acc[4] = {{0,0,0,0},{0,0,0,0},{0,0,0,0},{0,0,0,0}};
#pragma unroll
                for (int ks = 0; ks < 4; ++ks) {
                    const int q0 = ks * 16 + grp * 4;
                    const int ba = s * 1024 + cw * 64 + (q0 ^ (cw << 2));
                    bf16x8 bhf = *(const bf16x8*)&z1h_[ba];
                    bf16x8 blf = *(const bf16x8*)&z1l_[ba];
#pragma unroll
                    for (int ct = 0; ct < 4; ++ct) {
                        const int aa = (ct * 16 + cw) * 64 + (q0 ^ (cw << 2));
                        bf16x8 ah = *(const bf16x8*)&WA1h[aa];
                        bf16x8 al = *(const bf16x8*)&WA1l[aa];
                        MFMA(acc[ct], ah, bhf);
                        MFMA(acc[ct], al, bhf);
                        MFMA(acc[ct], ah, blf);
                    }
                }
#pragma unroll
                for (int ct = 0; ct < 4; ++ct) {
                    float v0 = fmaxf(acc[ct][0] + bAv[ct][0], 0.f);
                    float v1 = fmaxf(acc[ct][1] + bAv[ct][1], 0.f);
                    float v2 = fmaxf(acc[ct][2] + bAv[ct][2], 0.f);
                    float v3 = fmaxf(acc[ct][3] + bAv[ct][3], 0.f);
                    unsigned h01 = pack2_bf16(v0, v1), h23 = pack2_bf16(v2, v3);
                    unsigned l01 = pack2_bf16(v0 - __uint_as_float(h01 << 16),
                                              v1 - __uint_as_float(h01 & 0xFFFF0000u));
                    unsigned l23 = pack2_bf16(v2 - __uint_as_float(h23 << 16),
                                              v3 - __uint_as_float(h23 & 0xFFFF0000u));
                    const int q = ct * 8 + grp * 2;
                    const int wa = s * 512 + cw * 32 + (q ^ ((cw & 7) << 2));
                    *(uint2*)&h1h_[wa] = (uint2){ h01, h23 };
                    *(uint2*)&h1l_[wa] = (uint2){ l01, l23 };
                }
            }
        } else if (wid == 3 || wid == 7) {   // h2^T MFMA, chunk it-4 (ct split)
            const int c = it - 4;
            if (0 <= c && c < NCH) {
                const int s = c & 1;
                const int CT0 = (wid == 3) ? 0 : 2;
                f32x4 acc[2] = {{0,0,0,0},{0,0,0,0}};
#pragma unroll
                for (int ks = 0; ks < 4; ++ks) {
                    const int q0 = ks * 16 + grp * 4;
                    const int ba = s * 1024 + cw * 64 + (q0 ^ (cw << 2));
                    bf16x8 bhf = *(const bf16x8*)&z2h_[ba];
                    bf16x8 blf = *(const bf16x8*)&z2l_[ba];
#pragma unroll
                    for (int ct = 0; ct < 2; ++ct) {
                        const int aa = ((CT0 + ct) * 16 + cw) * 64 + (q0 ^ (cw << 2));
                        bf16x8 ah = *(const bf16x8*)&WA2h[aa];
                        bf16x8 al = *(const bf16x8*)&WA2l[aa];
                        MFMA(acc[ct], ah, bhf);
                        MFMA(acc[ct], al, bhf);
                        MFMA(acc[ct], ah, blf);
                    }
                }
#pragma unroll
                for (int ct = 0; ct < 2; ++ct) {
                    float v0 = fmaxf(acc[ct][0] + bAv[ct][0], 0.f);
                    float v1 = fmaxf(acc[ct][1] + bAv[ct][1], 0.f);
                    float v2 = fmaxf(acc[ct][2] + bAv[ct][2], 0.f);
                    float v3 = fmaxf(acc[ct][3] + bAv[ct][3], 0.f);
                    unsigned h01 = pack2_bf16(v0, v1), h23 = pack2_bf16(v2, v3);
                    unsigned l01 = pack2_bf16(v0 - __uint_as_float(h01 << 16),
                                              v1 - __uint_as_float(h01 & 0xFFFF0000u));
                    unsigned l23 = pack2_bf16(v2 - __uint_as_float(h23 << 16),
                                              v3 - __uint_as_float(h23 & 0xFFFF0000u));
                    const int q = (CT0 + ct) * 8 + grp * 2;
                    const int wa = s * 512 + cw * 32 + (q ^ ((cw & 7) << 2));
                    *(uint2*)&h2h_[wa] = (uint2){ h01, h23 };
                    *(uint2*)&h2l_[wa] = (uint2){ l01, l23 };
                }
            }
        } else if (wid == 4 || wid == 6) {   // x2^T MFMA, chunk it-2 (rt split)
            const int c = it - 2;
            if (0 <= c && c < NCH) {
                const int s = c & 1;
                const int RT0 = (wid == 4) ? 0 : 4;
                f32x4 acc[4] = {{0,0,0,0},{0,0,0,0},{0,0,0,0},{0,0,0,0}};
#pragma unroll
                for (int ks = 0; ks < 2; ++ks) {
                    const int q0 = ks * 16 + grp * 4;
                    const int ba = s * 512 + cw * 32 + (q0 ^ ((cw & 7) << 2));
                    bf16x8 bhf = *(const bf16x8*)&h1h_[ba];
                    bf16x8 blf = *(const bf16x8*)&h1l_[ba];
#pragma unroll
                    for (int rt = 0; rt < 4; ++rt) {
                        const int aa = ((RT0 + rt) * 16 + cw) * 32
                                       + (q0 ^ ((cw & 7) << 2));
                        bf16x8 ah = *(const bf16x8*)&W2Th[aa];
                        MFMA(acc[rt], ah, bhf);
                        MFMA(acc[rt], ah, blf);
                    }
                }
                unsigned* xs = x2p_ + s * 1280;
#pragma unroll
                for (int rt = 0; rt < 4; ++rt) {
                    float v0 = fmaxf(acc[rt][0] + bAv[rt][0], 0.f);
                    float v1 = fmaxf(acc[rt][1] + bAv[rt][1], 0.f);
                    float v2 = fmaxf(acc[rt][2] + bAv[rt][2], 0.f);
                    float v3 = fmaxf(acc[rt][3] + bAv[rt][3], 0.f);
                    const int p0 = (RT0 + rt) * 8 + grp * 2;
                    xs[p0 * 20 + cw]       = pack2_bf16(v0, v1);
                    xs[(p0 + 1) * 20 + cw] = pack2_bf16(v2, v3);
                }
            }
        } else {                             // wid==5: h3+logits(c-5), stage(c+1)
            const int cn = it + 1;
            if (cn < NCH) {                  // stage next chunk's forcing
                const int* xc = xb + cn * 16;
                unsigned* fd = fbuf + (cn & 1) * 1280;
#pragma unroll
                for (int j = 0; j < 16; ++j) {
                    unsigned v = tabP[(size_t)xc[j] * 64 + lane];
                    fd[lane * 20 + j] = v;
                }
            }
            const int c = it - 5;
            if (0 <= c && c < NCH) {
                const int s = c & 1;
                f32x4 c0 = {0,0,0,0}, c1 = {0,0,0,0};
#pragma unroll
                for (int ks = 0; ks < 2; ++ks) {
                    const int q0 = ks * 16 + grp * 4;
                    const int swz = q0 ^ ((cw & 7) << 2);
                    const int ba = s * 512 + cw * 32 + swz;
                    bf16x8 bhf = *(const bf16x8*)&h2h_[ba];
                    bf16x8 blf = *(const bf16x8*)&h2l_[ba];
                    bf16x8 a0h = *(const bf16x8*)&WPRh[cw * 32 + swz];
                    bf16x8 a0l = *(const bf16x8*)&WPRl[cw * 32 + swz];
                    MFMA(c0, a0h, bhf); MFMA(c0, a0l, bhf); MFMA(c0, a0h, blf);
                    bf16x8 a1h = *(const bf16x8*)&WPRh[(16 + cw) * 32 + swz];
                    bf16x8 a1l = *(const bf16x8*)&WPRl[(16 + cw) * 32 + swz];
                    MFMA(c1, a1h, bhf); MFMA(c1, a1l, bhf); MFMA(c1, a1h, blf);
                }
                float p0 = 0.f, p1 = 0.f;
#pragma unroll
                for (int r = 0; r < 4; ++r) {
                    float t0 = fast_tanh(c0[r] + bprv0[r]);
                    p0 = fmaf(t0, wh00[r], p0);
                    p1 = fmaf(t0, wh01[r], p1);
                    float t1 = fast_tanh(c1[r] + bprv1[r]);
                    p0 = fmaf(t1, wh10[r], p0);
                    p1 = fmaf(t1, wh11[r], p1);
                }
                p0 += __shfl_xor(p0, 16, 64); p0 += __shfl_xor(p0, 32, 64);
                p1 += __shfl_xor(p1, 16, 64); p1 += __shfl_xor(p1, 32, 64);
                if (grp == 0) {
                    float2 o = { p0 + bh0, p1 + bh1 };
                    *(float2*)&out[(size_t)b * (T_SEQ * 2) + (c * 16 + cw) * 2] = o;
                }
            }
        }
        __syncthreads();
    }
}

// ---------------------------------------------------------------------------
extern "C" void kernel_launch(void* const* d_in, const int* in_sizes, int n_in,
                              void* d_out, int out_size, void* d_ws, size_t ws_size,
                              hipStream_t stream) {
    const int*   x   = (const int*)  d_in[0];
    const float* E   = (const float*)d_in[1];
    const float* W1r = (const float*)d_in[2];
    const float* b1r = (const float*)d_in[3];
    const float* W1i = (const float*)d_in[4];
    const float* b1i = (const float*)d_in[5];
    const float* om1 = (const float*)d_in[6];
    const float* Wp1 = (const float*)d_in[7];
    const float* bp1 = (const float*)d_in[8];
    const float* W2r = (const float*)d_in[9];
    const float* b2r = (const float*)d_in[10];
    const float* W2i = (const float*)d_in[11];
    const float* b2i = (const float*)d_in[12];
    const float* om2 = (const float*)d_in[13];
    const float* Wp2 = (const float*)d_in[14];
    const float* bp2 = (const float*)d_in[15];
    const float* Wpr = (const float*)d_in[16];
    const float* bpr = (const float*)d_in[17];
    const float* Wh  = (const float*)d_in[18];
    const float* bh  = (const float*)d_in[19];

    unsigned* tabP = (unsigned*)d_ws;   // packed bf16 table [32000][64] — 8.2 MB

    k0_table<<<NVOC / 128, 256, 0, stream>>>(E, W1r, b1r, W1i, b1i, tabP);
    donn_pipe<<<B_BAT, 512, 0, stream>>>(tabP, x, om1, om2,
                                         Wp1, bp1, W2r, b2r, W2i, b2i,
                                         Wp2, bp2, Wpr, bpr, Wh, bh,
                                         (float*)d_out);
}